// Round 18
// baseline (78.352 us; speedup 1.0000x reference)
//
#include <hip/hip_runtime.h>
#include <math.h>

#define HWSZ 4096   // 64*64
#define DIM  64
#define KCW  512
#define NROW 131072 // 32*4096
#define CMAX 16
#define XP2  68     // x-tile pitch (floats)
#define WVS  5056   // floats per wave LDS slice (20224 B)

typedef short bf16x8 __attribute__((ext_vector_type(8)));
typedef float f32x4  __attribute__((ext_vector_type(4)));

// ws float layout: [64..576) csq; [1024..17408) bf16 blob; [17408..19456) wave loss partials
#define WS_CSQ  64
#define WS_BLOB 1024
#define WS_PART 17408

static __device__ __forceinline__ unsigned short f2bf(float f) {
    union { float f; unsigned u; } v; v.f = f;
    unsigned u = v.u;
    return (unsigned short)((u + 0x7fffu + ((u >> 16) & 1u)) >> 16);  // RNE
}

// prep: exact fp32 csq, codebook -> bf16 fragment blob
// blob[((kt*2+f)*64 + l)*8 + j] = bf16(cw[kt*16 + (l&15)][f*32 + (l>>4)*8 + j])
__global__ void vq_prep_kernel(const float* __restrict__ cw, float* __restrict__ ws) {
    int tg = blockIdx.x * 256 + threadIdx.x;
    if (tg < KCW) {
        const float4* c4 = (const float4*)(cw + (size_t)tg * DIM);
        float s0 = 0.f, s1 = 0.f, s2 = 0.f, s3 = 0.f;
        #pragma unroll
        for (int i = 0; i < 16; ++i) {
            float4 c = c4[i];
            s0 = fmaf(c.x, c.x, s0); s1 = fmaf(c.y, c.y, s1);
            s2 = fmaf(c.z, c.z, s2); s3 = fmaf(c.w, c.w, s3);
        }
        ws[WS_CSQ + tg] = (s0 + s1) + (s2 + s3);
    }
    if (tg < 4096) {
        int l = tg & 63, f = (tg >> 6) & 1, kt = tg >> 7;
        int col = kt * 16 + (l & 15);
        unsigned short* blob = (unsigned short*)(ws + WS_BLOB);
        #pragma unroll
        for (int j = 0; j < 8; ++j) {
            int d = f * 32 + (l >> 4) * 8 + j;
            blob[((kt * 2 + f) * 64 + l) * 8 + j] = f2bf(cw[col * DIM + d]);
        }
    }
}

// ZERO-BARRIER kernel, 64 rows/wave. 4 independent waves per 256-thr block;
// wave owns 64 CONSECUTIVE hw rows (256B full lines for every global access)
// and all 512 codewords. Per kt one B-fragment pair feeds 8 MFMA (4 row-
// groups) -> blob L2 stream halves vs R17 and ILP covers the load latency.
// waves_per_eu(2,2): LDS (81KB) caps at 2 blocks/CU = 8 waves/CU anyway, so
// pin the VGPR budget at 256 -- no allocator incentive to spill (R15/16
// lesson). Grid 512 = exactly 2 blocks/CU: whole grid resident, no tail.
__global__ __attribute__((amdgpu_flat_work_group_size(256, 256), amdgpu_waves_per_eu(2, 2)))
void vq_main_kernel(const float* __restrict__ in, const float* __restrict__ cw,
                    const float* __restrict__ ws_ro, float* __restrict__ part,
                    float* __restrict__ out) {
    __shared__ float lds[4 * WVS];

    const int t  = threadIdx.x;
    const int w  = t >> 6, l = t & 63;
    const int hi = l >> 4, cl = l & 15;

    float* S     = lds + w * WVS;            // wave-private slice
    float* xw    = S;                        // [64][XP2] fp32 x-tile (64 rows)
    float* xsq   = S + 4352;                 // [64]
    int*   sidxp = (int*)(S + 4416);         // [64]
    int*   cntsp = (int*)(S + 4480);         // [64]
    unsigned short* candp = (unsigned short*)(S + 4544);  // [64][16]

    const int b    = blockIdx.x >> 4;        // 16 blocks per image (256 rows each)
    const int hwW  = (blockIdx.x & 15) * 256 + w * 64;
    const int rowW = blockIdx.x * 256 + w * 64;

    cntsp[l] = 0;

    // ---- stage this wave's 64 rows x 64 dims (float4, 256B lines)
    const float* __restrict__ xg = in + (size_t)b * (DIM * HWSZ) + hwW;
    {
        const int tx = l & 15, dy = l >> 4;
        #pragma unroll
        for (int i = 0; i < 16; ++i) {
            int d = 4 * i + dy;
            *(float4*)(xw + d * XP2 + tx * 4) = *(const float4*)(xg + (size_t)d * HWSZ + tx * 4);
        }
    }

    // ---- exact ||x||^2: serial chain per row (reference rounding), lane = row
    {
        float s = 0.f;
        for (int d = 0; d < DIM; ++d) { float xv = xw[d * XP2 + l]; s = fmaf(xv, xv, s); }
        xsq[l] = s;
    }

    // ---- A fragments bf16(-x), 4 row-groups x 2 K-halves
    bf16x8 af[4][2];
    #pragma unroll
    for (int rgp = 0; rgp < 4; ++rgp)
        #pragma unroll
        for (int f = 0; f < 2; ++f)
            #pragma unroll
            for (int j = 0; j < 8; ++j)
                af[rgp][f][j] = (short)f2bf(-xw[(f * 32 + hi * 8 + j) * XP2 + rgp * 16 + cl]);

    const bf16x8* __restrict__ bp   = (const bf16x8*)(ws_ro + WS_BLOB);
    const float*  __restrict__ csqg = ws_ro + WS_CSQ;

    // ---- sweep 1: per-lane running min over all 32 kt, 4 row-groups
    float mn[4][4];
    #pragma unroll
    for (int rgp = 0; rgp < 4; ++rgp)
        #pragma unroll
        for (int rg = 0; rg < 4; ++rg) mn[rgp][rg] = INFINITY;
    #pragma unroll 2
    for (int kt = 0; kt < 32; ++kt) {
        float ci = 0.5f * csqg[kt * 16 + cl];
        bf16x8 b0 = bp[(kt * 2 + 0) * 64 + l];
        bf16x8 b1 = bp[(kt * 2 + 1) * 64 + l];
        #pragma unroll
        for (int rgp = 0; rgp < 4; ++rgp) {
            f32x4 a = {ci, ci, ci, ci};
            a = __builtin_amdgcn_mfma_f32_16x16x32_bf16(af[rgp][0], b0, a, 0, 0, 0);
            a = __builtin_amdgcn_mfma_f32_16x16x32_bf16(af[rgp][1], b1, a, 0, 0, 0);
            #pragma unroll
            for (int rg = 0; rg < 4; ++rg) mn[rgp][rg] = fminf(mn[rgp][rg], a[rg]);
        }
    }
    #pragma unroll
    for (int off = 1; off < 16; off <<= 1)      // row-min across 16 col-lanes: FINAL
        #pragma unroll
        for (int rgp = 0; rgp < 4; ++rgp)
            #pragma unroll
            for (int rg = 0; rg < 4; ++rg)
                mn[rgp][rg] = fminf(mn[rgp][rg], __shfl_xor(mn[rgp][rg], off, 64));

    // thresholds: marg = 2*beta + eps = 0.0625*||x|| + 0.03125 (R14-proven)
    float thr[4][4];
    #pragma unroll
    for (int rgp = 0; rgp < 4; ++rgp)
        #pragma unroll
        for (int rg = 0; rg < 4; ++rg)
            thr[rgp][rg] = mn[rgp][rg]
                         + 0.0625f * sqrtf(xsq[rgp * 16 + 4 * hi + rg]) + 0.03125f;

    // ---- sweep 2: recompute, capture vs FINAL threshold (tight set, ~1-3/row)
    #pragma unroll 2
    for (int kt = 0; kt < 32; ++kt) {
        float ci = 0.5f * csqg[kt * 16 + cl];
        bf16x8 b0 = bp[(kt * 2 + 0) * 64 + l];
        bf16x8 b1 = bp[(kt * 2 + 1) * 64 + l];
        #pragma unroll
        for (int rgp = 0; rgp < 4; ++rgp) {
            f32x4 a = {ci, ci, ci, ci};
            a = __builtin_amdgcn_mfma_f32_16x16x32_bf16(af[rgp][0], b0, a, 0, 0, 0);
            a = __builtin_amdgcn_mfma_f32_16x16x32_bf16(af[rgp][1], b1, a, 0, 0, 0);
            #pragma unroll
            for (int rg = 0; rg < 4; ++rg) {
                if (a[rg] <= thr[rgp][rg]) {
                    int r = rgp * 16 + 4 * hi + rg;      // wave-private row
                    int pos = atomicAdd(&cntsp[r], 1);
                    if (pos < CMAX) candp[r * 16 + pos] = (unsigned short)(kt * 16 + cl);
                }
            }
        }
    }

    // ---- exact fp32 refine: ONE lane per row, quad-sum order, lex tie-break
    {
        const int r = l;
        const int n = cntsp[r];
        if (n <= CMAX) {                         // n >= 1 (argmin always captured)
            float bb = INFINITY; int bkk = 0x7fffffff;
            const float xsqe = xsq[r];
            for (int s = 0; s < n; ++s) {
                int k = candp[r * 16 + s];
                const float4* __restrict__ c4 = (const float4*)(cw + (size_t)k * DIM);
                float d0 = 0.f, d1 = 0.f, d2 = 0.f, d3 = 0.f;
                #pragma unroll
                for (int i = 0; i < 16; ++i) {
                    float4 c = c4[i];
                    d0 = fmaf(xw[(4 * i + 0) * XP2 + r], c.x, d0);
                    d1 = fmaf(xw[(4 * i + 1) * XP2 + r], c.y, d1);
                    d2 = fmaf(xw[(4 * i + 2) * XP2 + r], c.z, d2);
                    d3 = fmaf(xw[(4 * i + 3) * XP2 + r], c.w, d3);
                }
                float dot  = (d0 + d1) + (d2 + d3);
                float dist = (xsqe + csqg[k]) - 2.f * dot;   // reference rounding order
                if (dist < bb || (dist == bb && k < bkk)) { bb = dist; bkk = k; }
            }
            sidxp[r] = bkk;
            out[(size_t)NROW * DIM + rowW + r] = (float)bkk;
        }
    }

    // ---- rare overflow rows (cnt > CMAX): wave-local exact full scan, 8 cols/lane
    for (int r = 0; r < 64; ++r) {
        if (cntsp[r] <= CMAX) continue;          // wave-uniform, deterministic count
        const float xsqe = xsq[r];
        float bb = INFINITY; int bkk = 0x7fffffff;
        for (int kk = 0; kk < 8; ++kk) {
            int k = kk * 64 + l;
            const float4* __restrict__ c4 = (const float4*)(cw + (size_t)k * DIM);
            float d0 = 0.f, d1 = 0.f, d2 = 0.f, d3 = 0.f;
            #pragma unroll
            for (int i = 0; i < 16; ++i) {
                float4 c = c4[i];
                d0 = fmaf(xw[(4 * i + 0) * XP2 + r], c.x, d0);
                d1 = fmaf(xw[(4 * i + 1) * XP2 + r], c.y, d1);
                d2 = fmaf(xw[(4 * i + 2) * XP2 + r], c.z, d2);
                d3 = fmaf(xw[(4 * i + 3) * XP2 + r], c.w, d3);
            }
            float dot  = (d0 + d1) + (d2 + d3);
            float dist = (xsqe + csqg[k]) - 2.f * dot;
            if (dist < bb || (dist == bb && k < bkk)) { bb = dist; bkk = k; }
        }
        #pragma unroll
        for (int off = 32; off; off >>= 1) {
            float ob = __shfl_down(bb, off, 64);
            int   ok = __shfl_down(bkk, off, 64);
            if (ob < bb || (ob == bb && ok < bkk)) { bb = ob; bkk = ok; }
        }
        if (l == 0) {
            sidxp[r] = bkk;
            out[(size_t)NROW * DIM + rowW + r] = (float)bkk;
        }
    }

    // ---- epilogue: ONE lane per row; writes are 256B full lines per d
    {
        const int r = l;
        const int kwin = sidxp[r];
        const float4* __restrict__ qp = (const float4*)(cw + (size_t)kwin * DIM);
        float* __restrict__ obase = out + (size_t)b * (DIM * HWSZ) + hwW + r;
        float lsum = 0.f;
        #pragma unroll
        for (int dd = 0; dd < 16; ++dd) {
            float4 q4 = qp[dd];
            float qv[4] = {q4.x, q4.y, q4.z, q4.w};
            #pragma unroll
            for (int c = 0; c < 4; ++c) {
                int d = dd * 4 + c;
                float xv = xw[d * XP2 + r];
                obase[(size_t)d * HWSZ] = qv[c];
                float diff = qv[c] - xv;
                lsum = fmaf(diff, diff, lsum);
            }
        }
        #pragma unroll
        for (int off = 32; off; off >>= 1) lsum += __shfl_down(lsum, off, 64);
        if (l == 0) part[blockIdx.x * 4 + w] = lsum;
    }
}

__global__ void vq_finalize_kernel(const float* __restrict__ part, float* __restrict__ out) {
    __shared__ float wsum[4];
    const int t = threadIdx.x;
    float s = 0.f;
    #pragma unroll
    for (int i = 0; i < 8; ++i) s += part[t * 8 + i];     // 2048 partials, fixed order
    #pragma unroll
    for (int off = 32; off; off >>= 1) s += __shfl_down(s, off, 64);
    if ((t & 63) == 0) wsum[t >> 6] = s;
    __syncthreads();
    if (t == 0)
        out[(size_t)NROW * DIM + NROW] =
            1.25f * ((wsum[0] + wsum[1]) + (wsum[2] + wsum[3])) / (float)((size_t)NROW * DIM);
}

extern "C" void kernel_launch(void* const* d_in, const int* in_sizes, int n_in,
                              void* d_out, int out_size, void* d_ws, size_t ws_size,
                              hipStream_t stream) {
    const float* in = (const float*)d_in[0];
    const float* cw = (const float*)d_in[1];
    float* out = (float*)d_out;
    float* ws  = (float*)d_ws;

    hipLaunchKernelGGL(vq_prep_kernel, dim3(16), dim3(256), 0, stream, cw, ws);
    hipLaunchKernelGGL(vq_main_kernel, dim3(NROW / 256), dim3(256), 0, stream,
                       in, cw, ws, ws + WS_PART, out);
    hipLaunchKernelGGL(vq_finalize_kernel, dim3(1), dim3(256), 0, stream, ws + WS_PART, out);
}

// Round 19
// 66.064 us; speedup vs baseline: 1.1860x; 1.1860x over previous
//
#include <hip/hip_runtime.h>
#include <math.h>

#define HWSZ 4096   // 64*64
#define DIM  64
#define KCW  512
#define NROW 131072 // 32*4096
#define CMAX 16

typedef short bf16x8 __attribute__((ext_vector_type(8)));
typedef float f32x4  __attribute__((ext_vector_type(4)));

// ws float layout: [64..576) csq; [1024..17408) bf16 blob; [17408..21504) wave loss partials
#define WS_CSQ  64
#define WS_BLOB 1024
#define WS_PART 17408

static __device__ __forceinline__ unsigned short f2bf(float f) {
    union { float f; unsigned u; } v; v.f = f;
    unsigned u = v.u;
    return (unsigned short)((u + 0x7fffu + ((u >> 16) & 1u)) >> 16);  // RNE
}

// prep: exact fp32 csq, codebook -> bf16 fragment blob
// blob[((kt*2+f)*64 + l)*8 + j] = bf16(cw[kt*16 + (l&15)][f*32 + (l>>4)*8 + j])
__global__ void vq_prep_kernel(const float* __restrict__ cw, float* __restrict__ ws) {
    int tg = blockIdx.x * 256 + threadIdx.x;
    if (tg < KCW) {
        const float4* c4 = (const float4*)(cw + (size_t)tg * DIM);
        float s0 = 0.f, s1 = 0.f, s2 = 0.f, s3 = 0.f;
        #pragma unroll
        for (int i = 0; i < 16; ++i) {
            float4 c = c4[i];
            s0 = fmaf(c.x, c.x, s0); s1 = fmaf(c.y, c.y, s1);
            s2 = fmaf(c.z, c.z, s2); s3 = fmaf(c.w, c.w, s3);
        }
        ws[WS_CSQ + tg] = (s0 + s1) + (s2 + s3);
    }
    if (tg < 4096) {
        int l = tg & 63, f = (tg >> 6) & 1, kt = tg >> 7;
        int col = kt * 16 + (l & 15);
        unsigned short* blob = (unsigned short*)(ws + WS_BLOB);
        #pragma unroll
        for (int j = 0; j < 8; ++j) {
            int d = f * 32 + (l >> 4) * 8 + j;
            blob[((kt * 2 + f) * 64 + l) * 8 + j] = f2bf(cw[col * DIM + d]);
        }
    }
}

// ONE-BARRIER kernel: 8 waves x 32 rows (512 thr, 256 rows/block, grid 512 ->
// 4096 waves = 16/CU resident, R17's winning wave count). The 64KB bf16 blob
// + csq live in BLOCK LDS (staged once, one __syncthreads) -> sweep loads are
// conflict-free ds_read_b128 instead of the 2x64KB/wave L2 stream that was
// R18's latency chain. x stays in GLOBAL (every access pattern is 128B
// coalesced + L2-hot; LDS has no room for both). Waves otherwise independent:
// wave-local min == global min, capture with final threshold (R15-18 chain).
__global__ __launch_bounds__(512, 4)
void vq_main_kernel(const float* __restrict__ in, const float* __restrict__ cw,
                    const float* __restrict__ ws_ro, float* __restrict__ part,
                    float* __restrict__ out) {
    __shared__ __align__(16) unsigned short blob_l[4096 * 8];  // 64 KB
    __shared__ float csq_l[KCW];                               // 2 KB
    __shared__ float xsqa[8][32];
    __shared__ int   sidxa[8][32];
    __shared__ int   cntsa[8][32];
    __shared__ unsigned short canda[8][32][CMAX];              // 8 KB

    const int t  = threadIdx.x;
    const int w  = t >> 6, l = t & 63;
    const int hi = l >> 4, cl = l & 15;

    const int b    = blockIdx.x >> 4;        // 16 blocks per image (256 rows each)
    const int hwW  = (blockIdx.x & 15) * 256 + w * 32;
    const int rowW = blockIdx.x * 256 + w * 32;

    // ---- stage blob + csq into block LDS (one coalesced pass)
    {
        const float4* __restrict__ bg = (const float4*)(ws_ro + WS_BLOB);
        float4* bl4 = (float4*)blob_l;
        #pragma unroll
        for (int i = 0; i < 8; ++i) bl4[i * 512 + t] = bg[i * 512 + t];
        csq_l[t] = ws_ro[WS_CSQ + t];
    }
    if (l < 32) cntsa[w][l] = 0;

    const float* __restrict__ xg = in + (size_t)b * (DIM * HWSZ) + hwW;

    // ---- exact ||x||^2 from global (reference serial rounding), lanes 0..31
    if (l < 32) {
        float s = 0.f;
        for (int d = 0; d < DIM; ++d) { float xv = xg[(size_t)d * HWSZ + l]; s = fmaf(xv, xv, s); }
        xsqa[w][l] = s;
    }

    // ---- A fragments bf16(-x) from global (L2-hot after first touch)
    bf16x8 a00, a01, a10, a11;
    #pragma unroll
    for (int j = 0; j < 8; ++j) {
        a00[j] = (short)f2bf(-xg[(size_t)(hi * 8 + j) * HWSZ + cl]);
        a01[j] = (short)f2bf(-xg[(size_t)(32 + hi * 8 + j) * HWSZ + cl]);
        a10[j] = (short)f2bf(-xg[(size_t)(hi * 8 + j) * HWSZ + 16 + cl]);
        a11[j] = (short)f2bf(-xg[(size_t)(32 + hi * 8 + j) * HWSZ + 16 + cl]);
    }

    __syncthreads();                          // blob_l/csq_l ready (the ONLY barrier)

    const bf16x8* __restrict__ bls = (const bf16x8*)blob_l;

    // ---- sweep 1: per-lane running min over all 32 kt, both row groups
    float mn0[4] = {INFINITY, INFINITY, INFINITY, INFINITY};
    float mn1[4] = {INFINITY, INFINITY, INFINITY, INFINITY};
    #pragma unroll 2
    for (int kt = 0; kt < 32; ++kt) {
        float ci = 0.5f * csq_l[kt * 16 + cl];
        bf16x8 b0 = bls[(kt * 2 + 0) * 64 + l];
        bf16x8 b1 = bls[(kt * 2 + 1) * 64 + l];
        f32x4 acc0 = {ci, ci, ci, ci};
        f32x4 acc1 = {ci, ci, ci, ci};
        acc0 = __builtin_amdgcn_mfma_f32_16x16x32_bf16(a00, b0, acc0, 0, 0, 0);
        acc0 = __builtin_amdgcn_mfma_f32_16x16x32_bf16(a01, b1, acc0, 0, 0, 0);
        acc1 = __builtin_amdgcn_mfma_f32_16x16x32_bf16(a10, b0, acc1, 0, 0, 0);
        acc1 = __builtin_amdgcn_mfma_f32_16x16x32_bf16(a11, b1, acc1, 0, 0, 0);
        #pragma unroll
        for (int rg = 0; rg < 4; ++rg) {
            mn0[rg] = fminf(mn0[rg], acc0[rg]);
            mn1[rg] = fminf(mn1[rg], acc1[rg]);
        }
    }
    #pragma unroll
    for (int off = 1; off < 16; off <<= 1)    // row-min across 16 col-lanes: FINAL
        #pragma unroll
        for (int rg = 0; rg < 4; ++rg) {
            mn0[rg] = fminf(mn0[rg], __shfl_xor(mn0[rg], off, 64));
            mn1[rg] = fminf(mn1[rg], __shfl_xor(mn1[rg], off, 64));
        }

    // thresholds: marg = 2*beta + eps = 0.0625*||x|| + 0.03125 (R14-proven)
    float thr0[4], thr1[4];
    #pragma unroll
    for (int rg = 0; rg < 4; ++rg) {
        thr0[rg] = mn0[rg] + 0.0625f * sqrtf(xsqa[w][4 * hi + rg]) + 0.03125f;
        thr1[rg] = mn1[rg] + 0.0625f * sqrtf(xsqa[w][16 + 4 * hi + rg]) + 0.03125f;
    }

    // ---- sweep 2: recompute (LDS loads), capture vs FINAL threshold
    #pragma unroll 2
    for (int kt = 0; kt < 32; ++kt) {
        float ci = 0.5f * csq_l[kt * 16 + cl];
        bf16x8 b0 = bls[(kt * 2 + 0) * 64 + l];
        bf16x8 b1 = bls[(kt * 2 + 1) * 64 + l];
        f32x4 acc0 = {ci, ci, ci, ci};
        f32x4 acc1 = {ci, ci, ci, ci};
        acc0 = __builtin_amdgcn_mfma_f32_16x16x32_bf16(a00, b0, acc0, 0, 0, 0);
        acc0 = __builtin_amdgcn_mfma_f32_16x16x32_bf16(a01, b1, acc0, 0, 0, 0);
        acc1 = __builtin_amdgcn_mfma_f32_16x16x32_bf16(a10, b0, acc1, 0, 0, 0);
        acc1 = __builtin_amdgcn_mfma_f32_16x16x32_bf16(a11, b1, acc1, 0, 0, 0);
        #pragma unroll
        for (int rg = 0; rg < 4; ++rg) {
            if (acc0[rg] <= thr0[rg]) {
                int r = 4 * hi + rg;
                int pos = atomicAdd(&cntsa[w][r], 1);
                if (pos < CMAX) canda[w][r][pos] = (unsigned short)(kt * 16 + cl);
            }
            if (acc1[rg] <= thr1[rg]) {
                int r = 16 + 4 * hi + rg;
                int pos = atomicAdd(&cntsa[w][r], 1);
                if (pos < CMAX) canda[w][r][pos] = (unsigned short)(kt * 16 + cl);
            }
        }
    }

    // ---- exact fp32 refine: 2 lanes/row, x from global (coalesced, L2-hot)
    {
        const int r = l >> 1, q = l & 1;
        const int n = cntsa[w][r];
        const float* __restrict__ xr = xg + r;
        if (n <= CMAX) {                       // n >= 1 (argmin always captured)
            float bb = INFINITY; int bkk = 0x7fffffff;
            const float xsqe = xsqa[w][r];
            for (int s = q; s < n; s += 2) {
                int k = canda[w][r][s];
                const float4* __restrict__ c4 = (const float4*)(cw + (size_t)k * DIM);
                float d0 = 0.f, d1 = 0.f, d2 = 0.f, d3 = 0.f;
                #pragma unroll
                for (int i = 0; i < 16; ++i) {
                    float4 c = c4[i];
                    d0 = fmaf(xr[(size_t)(4 * i + 0) * HWSZ], c.x, d0);
                    d1 = fmaf(xr[(size_t)(4 * i + 1) * HWSZ], c.y, d1);
                    d2 = fmaf(xr[(size_t)(4 * i + 2) * HWSZ], c.z, d2);
                    d3 = fmaf(xr[(size_t)(4 * i + 3) * HWSZ], c.w, d3);
                }
                float dot  = (d0 + d1) + (d2 + d3);
                float dist = (xsqe + csq_l[k]) - 2.f * dot;  // reference rounding order
                if (dist < bb || (dist == bb && k < bkk)) { bb = dist; bkk = k; }
            }
            {
                float ob = __shfl_xor(bb, 1, 64);
                int   ok = __shfl_xor(bkk, 1, 64);
                if (ob < bb || (ob == bb && ok < bkk)) { bb = ob; bkk = ok; }
            }
            if (q == 0) {
                sidxa[w][r] = bkk;
                out[(size_t)NROW * DIM + rowW + r] = (float)bkk;
            }
        }
    }

    // ---- rare overflow rows (cnt > CMAX): wave-local exact full scan
    for (int r = 0; r < 32; ++r) {
        if (cntsa[w][r] <= CMAX) continue;     // wave-uniform count
        const float xsqe = xsqa[w][r];
        const float* __restrict__ xr = xg + r;
        float bb = INFINITY; int bkk = 0x7fffffff;
        for (int kk = 0; kk < 8; ++kk) {
            int k = kk * 64 + l;
            const float4* __restrict__ c4 = (const float4*)(cw + (size_t)k * DIM);
            float d0 = 0.f, d1 = 0.f, d2 = 0.f, d3 = 0.f;
            #pragma unroll
            for (int i = 0; i < 16; ++i) {
                float4 c = c4[i];
                d0 = fmaf(xr[(size_t)(4 * i + 0) * HWSZ], c.x, d0);
                d1 = fmaf(xr[(size_t)(4 * i + 1) * HWSZ], c.y, d1);
                d2 = fmaf(xr[(size_t)(4 * i + 2) * HWSZ], c.z, d2);
                d3 = fmaf(xr[(size_t)(4 * i + 3) * HWSZ], c.w, d3);
            }
            float dot  = (d0 + d1) + (d2 + d3);
            float dist = (xsqe + csq_l[k]) - 2.f * dot;
            if (dist < bb || (dist == bb && k < bkk)) { bb = dist; bkk = k; }
        }
        #pragma unroll
        for (int off = 32; off; off >>= 1) {
            float ob = __shfl_down(bb, off, 64);
            int   ok = __shfl_down(bkk, off, 64);
            if (ob < bb || (ob == bb && ok < bkk)) { bb = ob; bkk = ok; }
        }
        if (l == 0) {
            sidxa[w][r] = bkk;
            out[(size_t)NROW * DIM + rowW + r] = (float)bkk;
        }
    }

    // ---- epilogue: 2 lanes/row (32 dims each); full-128B-line stores
    {
        const int r = l >> 1, q2 = l & 1;
        const int kwin = sidxa[w][r];
        const float4* __restrict__ qp = (const float4*)(cw + (size_t)kwin * DIM + q2 * 32);
        const float* __restrict__ xe = xg + r;
        float* __restrict__ obase = out + (size_t)b * (DIM * HWSZ) + hwW + r;
        float lsum = 0.f;
        #pragma unroll
        for (int dd = 0; dd < 8; ++dd) {
            float4 q4 = qp[dd];
            float qv[4] = {q4.x, q4.y, q4.z, q4.w};
            #pragma unroll
            for (int c = 0; c < 4; ++c) {
                int d = q2 * 32 + dd * 4 + c;
                float xv = xe[(size_t)d * HWSZ];
                obase[(size_t)d * HWSZ] = qv[c];
                float diff = qv[c] - xv;
                lsum = fmaf(diff, diff, lsum);
            }
        }
        #pragma unroll
        for (int off = 32; off; off >>= 1) lsum += __shfl_down(lsum, off, 64);
        if (l == 0) part[blockIdx.x * 8 + w] = lsum;
    }
}

__global__ void vq_finalize_kernel(const float* __restrict__ part, float* __restrict__ out) {
    __shared__ float wsum[4];
    const int t = threadIdx.x;
    float s = 0.f;
    #pragma unroll
    for (int i = 0; i < 16; ++i) s += part[t * 16 + i];   // 4096 partials, fixed order
    #pragma unroll
    for (int off = 32; off; off >>= 1) s += __shfl_down(s, off, 64);
    if ((t & 63) == 0) wsum[t >> 6] = s;
    __syncthreads();
    if (t == 0)
        out[(size_t)NROW * DIM + NROW] =
            1.25f * ((wsum[0] + wsum[1]) + (wsum[2] + wsum[3])) / (float)((size_t)NROW * DIM);
}

extern "C" void kernel_launch(void* const* d_in, const int* in_sizes, int n_in,
                              void* d_out, int out_size, void* d_ws, size_t ws_size,
                              hipStream_t stream) {
    const float* in = (const float*)d_in[0];
    const float* cw = (const float*)d_in[1];
    float* out = (float*)d_out;
    float* ws  = (float*)d_ws;

    hipLaunchKernelGGL(vq_prep_kernel, dim3(16), dim3(256), 0, stream, cw, ws);
    hipLaunchKernelGGL(vq_main_kernel, dim3(NROW / 256), dim3(512), 0, stream,
                       in, cw, ws, ws + WS_PART, out);
    hipLaunchKernelGGL(vq_finalize_kernel, dim3(1), dim3(256), 0, stream, ws + WS_PART, out);
}